// Round 9
// baseline (95.816 us; speedup 1.0000x reference)
//
#include <hip/hip_runtime.h>
#include <math.h>

#define BB   128
#define SS   2048
#define DIN  1024
#define DSRC 1024
#define DOUT 1024
#define WW   64
#define WLEN 129
#define HH   512
#define WCH  17     // w-chunk per score block; 8 chunks cover 136 >= 129
#define GW   136    // gaussian table width (WLEN padded)

// workspace layout (bytes)
#define OFF_WSI   0
#define OFF_P     512
#define OFF_LEN   1024
#define OFF_GTAB  4096        // float[128][136] -> ends 73728
#define OFF_X32   73728       // float[128][1024] = 512 KB
#define OFF_OPI   598016      // float[128][1024] = 512 KB (input-half of out GEMM, final)
#define OFF_Z1P   1122304     // double[4][128][512] = 2 MB
#define OFF_CPART 3219456     // float[128][8][1024] = 4 MB
#define OFF_MPART 7413760
#define OFF_LPART 7417856
#define OFF_SPART 7421952     // float[128][8][17]
#define OFF_OP    7491584     // float[4][128][1024] = 2 MB (c-half partials)
#define WS_NEED   9588736

// d_out layout (floats)
#define DO_A    (BB*DOUT)        // 131072
#define DO_WS   (DO_A + BB*WLEN) // 147584
#define DO_WE   (DO_WS + BB)     // 147712

// ---------------- 16-col tiled GEMM stage (R3-proven; f32 products, f64 chunk accumulation) ------
template<int NTOT, int KRANGE, bool F64OUT>
__device__ __forceinline__ void gemm16(const int gblk, const int t,
    const float* __restrict__ A, const int lda,
    const float* __restrict__ Wt, const int ldw,
    void* __restrict__ outp, float* __restrict__ alds /* [64][130] */)
{
    constexpr int NJB = NTOT / 16;
    const int jb = gblk % NJB;
    const int ks = gblk / NJB;
    const int lane = t & 63;
    const int wvid = __builtin_amdgcn_readfirstlane(t >> 6);
    const int j0 = jb * 16 + wvid * 2;
    const int k0 = ks * KRANGE;

    double dac[2][2];
    dac[0][0] = 0.0; dac[0][1] = 0.0; dac[1][0] = 0.0; dac[1][1] = 0.0;

    const float* wbase = Wt + (size_t)j0 * ldw;

    for (int kc = 0; kc < KRANGE; kc += 64) {
        const int kg = k0 + kc;
        __syncthreads();
        #pragma unroll
        for (int q = 0; q < 4; ++q) {
            const int f4 = t + 512 * q;
            const int bb = f4 >> 4, c4 = f4 & 15;
            const float4 v = *reinterpret_cast<const float4*>(A + (size_t)bb * lda + kg + c4 * 4);
            alds[(c4*4+0)*130 + bb] = v.x;
            alds[(c4*4+1)*130 + bb] = v.y;
            alds[(c4*4+2)*130 + bb] = v.z;
            alds[(c4*4+3)*130 + bb] = v.w;
        }
        __syncthreads();
        const float* wr = wbase + kg;
        #pragma unroll
        for (int kk16 = 0; kk16 < 64; kk16 += 16) {
            float fa[2][2];
            fa[0][0] = 0.f; fa[0][1] = 0.f; fa[1][0] = 0.f; fa[1][1] = 0.f;
            #pragma unroll
            for (int kk = 0; kk < 16; ++kk) {
                const int k = kk16 + kk;
                const float2 av = *reinterpret_cast<const float2*>(&alds[k*130 + 2*lane]);
                #pragma unroll
                for (int jj = 0; jj < 2; ++jj) {
                    const float wvv = wr[jj*ldw + k];
                    fa[jj][0] = fmaf(wvv, av.x, fa[jj][0]);
                    fa[jj][1] = fmaf(wvv, av.y, fa[jj][1]);
                }
            }
            #pragma unroll
            for (int jj = 0; jj < 2; ++jj) {
                dac[jj][0] += (double)fa[jj][0];
                dac[jj][1] += (double)fa[jj][1];
            }
        }
    }
    #pragma unroll
    for (int i = 0; i < 2; ++i) {
        const int b = 2*lane + i;
        const size_t base = ((size_t)ks * BB + b) * NTOT + j0;
        if constexpr (F64OUT) {
            double* o = (double*)outp;
            o[base + 0] = dac[0][i];
            o[base + 1] = dac[1][i];
        } else {
            float* o = (float*)outp;
            o[base + 0] = (float)dac[0][i];
            o[base + 1] = (float)dac[1][i];
        }
    }
}

// ---------------- L1: combo = gemm1 full-K (128) | gemm2i full-K (128) | lengths (128) -----------
// Full-K 8-col blocks: 8 waves x 1 col, lanes hold 2 rows; register chunk prefetch.
// 384 blocks x 8 waves = 3 waves/SIMD. x32/opi written FINAL (xred eliminated).
__global__ __launch_bounds__(512)
void k_combo(const float* __restrict__ input, const float* __restrict__ Wi,
             const float* __restrict__ Wo, const unsigned char* __restrict__ mask,
             float* __restrict__ x32, float* __restrict__ opi, int* __restrict__ lengths)
{
    __shared__ __align__(16) float alds[64*130];
    const int blk = blockIdx.x, t = threadIdx.x;
    const int lane = t & 63;
    const int wv = __builtin_amdgcn_readfirstlane(t >> 6);

    if (blk < 256) {
        const bool isX = (blk < 128);
        const int j = (isX ? blk : blk - 128) * 8 + wv;
        const float* wr0 = isX ? (Wi + (size_t)j * DIN)
                               : (Wo + (size_t)j * (DIN + DSRC) + 1024);
        double dac0 = 0.0, dac1 = 0.0;

        float4 pf[4];
        #pragma unroll
        for (int q = 0; q < 4; ++q) {
            const int f4 = t + 512*q;
            const int bb = f4 >> 4, c4 = f4 & 15;
            pf[q] = *reinterpret_cast<const float4*>(input + (size_t)bb*DIN + c4*4);
        }
        for (int c = 0; c < 16; ++c) {
            __syncthreads();
            #pragma unroll
            for (int q = 0; q < 4; ++q) {
                const int f4 = t + 512*q;
                const int bb = f4 >> 4, c4 = f4 & 15;
                alds[(c4*4+0)*130 + bb] = pf[q].x;
                alds[(c4*4+1)*130 + bb] = pf[q].y;
                alds[(c4*4+2)*130 + bb] = pf[q].z;
                alds[(c4*4+3)*130 + bb] = pf[q].w;
            }
            __syncthreads();
            if (c + 1 < 16) {
                #pragma unroll
                for (int q = 0; q < 4; ++q) {
                    const int f4 = t + 512*q;
                    const int bb = f4 >> 4, c4 = f4 & 15;
                    pf[q] = *reinterpret_cast<const float4*>(input + (size_t)bb*DIN + (c+1)*64 + c4*4);
                }
            }
            const float* wr = wr0 + c*64;
            #pragma unroll
            for (int kk16 = 0; kk16 < 64; kk16 += 16) {
                float fa0 = 0.f, fa1 = 0.f;
                #pragma unroll
                for (int kk = 0; kk < 16; ++kk) {
                    const int k = kk16 + kk;
                    const float2 av = *reinterpret_cast<const float2*>(&alds[k*130 + 2*lane]);
                    const float wvv = wr[k];
                    fa0 = fmaf(wvv, av.x, fa0);
                    fa1 = fmaf(wvv, av.y, fa1);
                }
                dac0 += (double)fa0;
                dac1 += (double)fa1;
            }
        }
        float* dst = isX ? x32 : opi;
        dst[(size_t)(2*lane    )*1024 + j] = (float)dac0;
        dst[(size_t)(2*lane + 1)*1024 + j] = (float)dac1;
    } else {
        const int b = blk - 256;
        const bool is_u8 = (mask[(size_t)SS*BB - 1] != 0);
        int cnt = 0;
        if (is_u8) {
            #pragma unroll
            for (int q = 0; q < 4; ++q)
                cnt += (mask[(size_t)(t + 512*q)*BB + b] != 0) ? 1 : 0;
        } else {
            const int* m32 = (const int*)mask;
            #pragma unroll
            for (int q = 0; q < 4; ++q)
                cnt += (m32[(size_t)(t + 512*q)*BB + b] != 0) ? 1 : 0;
        }
        int* red = (int*)alds;
        red[t] = cnt;
        __syncthreads();
        for (int st = 256; st >= 1; st >>= 1) {
            if (t < st) red[t] += red[t + st];
            __syncthreads();
        }
        if (t == 0) lengths[b] = SS - red[0];
    }
}

// ---------------- L2: fc1 partials = x32 @ W1^T (R3 verbatim) ----------------
__global__ __launch_bounds__(512)
void k_fc1(const float* __restrict__ x32, const float* __restrict__ W1, double* __restrict__ z1p)
{
    __shared__ __align__(16) float alds[64*130];
    gemm16<512, 256, true>(blockIdx.x, threadIdx.x, x32, DSRC, W1, DIN, z1p, alds);
}

// ---------------- L3: fc2: z1 reduce + tanh + dot(W2) + sigmoid -> W0, p, gtab, ws/we ------------
__global__ __launch_bounds__(64)
void k_fc2(const double* __restrict__ z1p, const float* __restrict__ b1,
           const float* __restrict__ W2f, const float* __restrict__ b2,
           const int* __restrict__ lengths, int* __restrict__ wsi,
           float* __restrict__ pbuf, float* __restrict__ gtab, float* __restrict__ dout)
{
    const int b = blockIdx.x, lane = threadIdx.x;
    double part = 0.0;
    #pragma unroll
    for (int q = 0; q < 8; ++q) {
        const int h = lane + 64*q;
        double z = 0.0;
        #pragma unroll
        for (int ks = 0; ks < 4; ++ks) z += z1p[((size_t)ks*BB + b)*HH + h];
        z += (double)b1[h];
        part += tanh(z) * (double)W2f[h];
    }
    #pragma unroll
    for (int off = 32; off >= 1; off >>= 1) part += __shfl_xor(part, off);
    const double z2  = part + (double)b2[0];
    const double sig = 1.0 / (1.0 + exp(-z2));
    const double wsf = (double)lengths[b] * sig;   // p - W
    int W0 = (int)rint(wsf);
    if (W0 < 0) W0 = 0;
    if (W0 > SS - WLEN) W0 = SS - WLEN;
    const float pf = (float)(wsf + 64.0);
    if (lane == 0) {
        wsi[b]  = W0;
        pbuf[b] = pf;
        dout[DO_WS + b] = (float)W0;
        dout[DO_WE + b] = (float)(W0 + WLEN);
    }
    #pragma unroll
    for (int q = 0; q < 3; ++q) {
        const int w = lane + 64*q;
        if (w < GW) {
            float g = 0.f;
            if (w < WLEN) {
                const float d = (float)(W0 + w) - pf;
                g = expf(d*d * (-1.0f/2048.0f));
            }
            gtab[b*GW + w] = g;
        }
    }
}

// ---------------- L4: per-(b, w-chunk) scores + local softmax + partial c (R3 verbatim) ----------
__global__ __launch_bounds__(256)
void k_score(const float* __restrict__ x32, const float* __restrict__ src,
             const int* __restrict__ wsi, const float* __restrict__ pbuf,
             const int* __restrict__ lengths, const float* __restrict__ gtab,
             float* __restrict__ cpart, float* __restrict__ mpart,
             float* __restrict__ lpart, float* __restrict__ spart)
{
    const int wc = blockIdx.x, b = blockIdx.y;
    const int t = threadIdx.x, lane = t & 63, wv = t >> 6;
    const int   w0 = wsi[b];
    const int   L  = lengths[b];

    const float4 x4 = *reinterpret_cast<const float4*>(x32 + b*DSRC + 4*t);

    float4 sel[WCH];
    #pragma unroll
    for (int i = 0; i < WCH; ++i) {
        const int w = wc*WCH + i;
        if (w < WLEN) {
            const size_t off = ((size_t)(w0 + w) * BB + b) * DSRC + 4*t;
            sel[i] = *reinterpret_cast<const float4*>(src + off);
        } else sel[i] = make_float4(0.f, 0.f, 0.f, 0.f);
    }

    float w_[32];
    #pragma unroll
    for (int i = 0; i < WCH; ++i)
        w_[i] = fmaf(x4.x, sel[i].x, fmaf(x4.y, sel[i].y, fmaf(x4.z, sel[i].z, x4.w * sel[i].w)));
    #pragma unroll
    for (int i = WCH; i < 32; ++i) w_[i] = 0.f;

    #pragma unroll
    for (int k = 0; k < 5; ++k) {
        const int dist = 1 << k;
        const bool hi = (lane >> k) & 1;
        const int n2 = 32 >> (k + 1);
        #pragma unroll
        for (int i = 0; i < n2; ++i) {
            const float keep = hi ? w_[2*i+1] : w_[2*i];
            const float send = hi ? w_[2*i]   : w_[2*i+1];
            w_[i] = keep + __shfl_xor(send, dist);
        }
    }
    const float tot = w_[0] + __shfl_xor(w_[0], 32);   // full 64-lane sum of row (lane&31)

    __shared__ float red[WCH][4];
    __shared__ float s_sh[WCH];
    if (lane < WCH) red[lane][wv] = tot;
    __syncthreads();
    if (t < WCH) {
        const int w = wc*WCH + t;
        float s;
        if (w < WLEN) {
            const float sum = red[t][0] + red[t][1] + red[t][2] + red[t][3];
            const int pos = w0 + w;
            s = (pos >= WW && pos < L + WW) ? sum : 1e-14f;
        } else s = -INFINITY;
        s_sh[t] = s;
    }
    __syncthreads();

    float sv[WCH];
    #pragma unroll
    for (int i = 0; i < WCH; ++i) sv[i] = s_sh[i];
    float m_loc = -INFINITY;
    #pragma unroll
    for (int i = 0; i < WCH; ++i) m_loc = fmaxf(m_loc, sv[i]);
    float l_loc = 0.f;
    float4 c = make_float4(0.f, 0.f, 0.f, 0.f);
    #pragma unroll
    for (int i = 0; i < WCH; ++i) {
        const float e = expf(sv[i] - m_loc);       // -inf -> 0 for w >= WLEN
        l_loc += e;
        const float g = gtab[b*GW + wc*WCH + i];   // 0 beyond WLEN
        const float wt = e * g;
        c.x = fmaf(wt, sel[i].x, c.x);
        c.y = fmaf(wt, sel[i].y, c.y);
        c.z = fmaf(wt, sel[i].z, c.z);
        c.w = fmaf(wt, sel[i].w, c.w);
    }
    *reinterpret_cast<float4*>(cpart + ((size_t)(b*8 + wc))*DSRC + 4*t) = c;
    if (t == 0) { mpart[b*8 + wc] = m_loc; lpart[b*8 + wc] = l_loc; }
    if (t < WCH) spart[(b*8 + wc)*WCH + t] = s_sh[t];
}

// ---------------- L5: merge 8 partials per b -> c32 + a output (R3 verbatim) ----------------
__global__ __launch_bounds__(256)
void k_merge(const float* __restrict__ cpart, const float* __restrict__ mpart,
             const float* __restrict__ lpart, const float* __restrict__ spart,
             const float* __restrict__ gtab, float* __restrict__ c32,
             float* __restrict__ dout)
{
    const int b = blockIdx.x, t = threadIdx.x;
    __shared__ float mv[8], lv[8];
    if (t < 8) { mv[t] = mpart[b*8 + t]; lv[t] = lpart[b*8 + t]; }
    __syncthreads();
    float m = -INFINITY;
    #pragma unroll
    for (int i = 0; i < 8; ++i) m = fmaxf(m, mv[i]);
    float l = 0.f;
    float fac[8];
    #pragma unroll
    for (int i = 0; i < 8; ++i) { fac[i] = expf(mv[i] - m); l = fmaf(lv[i], fac[i], l); }
    const float inv = 1.0f / l;

    float4 c = make_float4(0.f, 0.f, 0.f, 0.f);
    #pragma unroll
    for (int i = 0; i < 8; ++i) {
        const float4 cp = *reinterpret_cast<const float4*>(cpart + ((size_t)(b*8 + i))*DSRC + 4*t);
        c.x = fmaf(cp.x, fac[i], c.x);
        c.y = fmaf(cp.y, fac[i], c.y);
        c.z = fmaf(cp.z, fac[i], c.z);
        c.w = fmaf(cp.w, fac[i], c.w);
    }
    c.x *= inv; c.y *= inv; c.z *= inv; c.w *= inv;
    *reinterpret_cast<float4*>(c32 + (size_t)b*DSRC + 4*t) = c;

    if (t < WLEN) {
        const int wc = t / WCH, i = t % WCH;
        const float s = spart[(b*8 + wc)*WCH + i];
        const float g = gtab[b*GW + t];
        dout[DO_A + b*WLEN + t] = expf(s - m) * inv * g;
    }
}

// ---------------- L6: op[0..3] = c32 @ Wo[:, :1024]^T (R3 verbatim) ----------------
__global__ __launch_bounds__(512)
void k_gemm2c(const float* __restrict__ c32, const float* __restrict__ Wo, float* __restrict__ op)
{
    __shared__ __align__(16) float alds[64*130];
    gemm16<1024, 256, false>(blockIdx.x, threadIdx.x, c32, DSRC, Wo, DIN + DSRC, op, alds);
}

// ---------------- L7: reduce 4 op partials + opi + tanh -> out ----------------
__global__ __launch_bounds__(512)
void k_outred(const float* __restrict__ op, const float* __restrict__ opi,
              float* __restrict__ dout)
{
    const int i = blockIdx.x * 512 + threadIdx.x;
    float s = 0.f;
    #pragma unroll
    for (int ks = 0; ks < 4; ++ks) s += op[(size_t)ks * (BB*DOUT) + i];
    s += opi[i];
    dout[i] = tanhf(s);
}

extern "C" void kernel_launch(void* const* d_in, const int* in_sizes, int n_in,
                              void* d_out, int out_size, void* d_ws, size_t ws_size,
                              hipStream_t stream)
{
    const float* input = (const float*)d_in[0];
    const float* src   = (const float*)d_in[1];
    const unsigned char* mask = (const unsigned char*)d_in[2];
    const float* Wi = (const float*)d_in[3];
    const float* Wo = (const float*)d_in[4];
    const float* W1 = (const float*)d_in[5];
    const float* b1 = (const float*)d_in[6];
    const float* W2 = (const float*)d_in[7];
    const float* b2 = (const float*)d_in[8];
    float* out = (float*)d_out;

    if (ws_size < (size_t)WS_NEED) return;

    char* ws = (char*)d_ws;
    int*    wsi     = (int*)   (ws + OFF_WSI);
    float*  pbuf    = (float*) (ws + OFF_P);
    int*    lengths = (int*)   (ws + OFF_LEN);
    float*  gtab    = (float*) (ws + OFF_GTAB);
    float*  x32     = (float*) (ws + OFF_X32);
    float*  opi     = (float*) (ws + OFF_OPI);
    double* z1p     = (double*)(ws + OFF_Z1P);
    float*  cpart   = (float*) (ws + OFF_CPART);
    float*  mpart   = (float*) (ws + OFF_MPART);
    float*  lpart   = (float*) (ws + OFF_LPART);
    float*  spart   = (float*) (ws + OFF_SPART);
    float*  op      = (float*) (ws + OFF_OP);
    float*  c32     = x32;   // x32 dead after k_score; reuse slot for c32

    // L1: x32 = in@Wi^T (full-K, final) || opi = in@Wo_i^T (full-K, final) || lengths
    k_combo<<<384, 512, 0, stream>>>(input, Wi, Wo, mask, x32, opi, lengths);
    // L2: z1 partials = x32 @ W1^T
    k_fc1<<<128, 512, 0, stream>>>(x32, W1, z1p);
    // L3: fc2 -> W0/p/gtab/ws/we
    k_fc2<<<128, 64, 0, stream>>>(z1p, b1, W2, b2, lengths, wsi, pbuf, gtab, out);
    // L4: scores + local softmax + partial c
    k_score<<<dim3(8,128), 256, 0, stream>>>(x32, src, wsi, pbuf, lengths, gtab,
                                             cpart, mpart, lpart, spart);
    // L5: merge partials -> c32 + a   (c32 reuses the dead x32 slot)
    k_merge<<<128, 256, 0, stream>>>(cpart, mpart, lpart, spart, gtab, c32, out);
    // L6: op[0..3] = c32 @ Wo_c^T
    k_gemm2c<<<256, 512, 0, stream>>>(c32, Wo, op);
    // L7: out = tanh(sum op + opi)
    k_outred<<<256, 512, 0, stream>>>(op, opi, out);
}

// Round 10
// 85.458 us; speedup vs baseline: 1.1212x; 1.1212x over previous
//
#include <hip/hip_runtime.h>
#include <math.h>

#define BB   128
#define SS   2048
#define DIN  1024
#define DSRC 1024
#define DOUT 1024
#define WW   64
#define WLEN 129
#define HH   512
#define WCH  17     // w-chunk per score block; 8 chunks cover 136 >= 129
#define GW   136    // gaussian table width (WLEN padded)

// workspace layout (bytes)
#define OFF_WSI   0
#define OFF_P     512
#define OFF_LEN   1024
#define OFF_GTAB  4096        // float[128][136] -> ends 73728
#define OFF_XP    73728       // double[4][128][1024] = 4 MB
#define OFF_X32   4268032     // float[128][1024]
#define OFF_Z1P   4792320     // double[4][128][512] = 2 MB
#define OFF_C32   6889472     // float[128][1024]
#define OFF_CPART 7413760     // float[128][8][1024] = 4 MB
#define OFF_MPART 11608064
#define OFF_LPART 11612160
#define OFF_SPART 11616256    // float[128][8][17]
#define OFF_OPC   11685888    // float[8][128][1024] = 4 MB (c-half partials)
#define OFF_OPI   15880192    // float[4][128][1024] = 2 MB (input-half partials)
#define WS_NEED   17977344    // ~18 MB (R0 used 17.8 MB successfully)

// d_out layout (floats)
#define DO_A    (BB*DOUT)        // 131072
#define DO_WS   (DO_A + BB*WLEN) // 147584
#define DO_WE   (DO_WS + BB)     // 147712

// ---------------- 16-col tiled GEMM stage (R3-proven) ----------------
template<int NTOT, int KRANGE, bool F64OUT>
__device__ __forceinline__ void gemm16(const int gblk, const int t,
    const float* __restrict__ A, const int lda,
    const float* __restrict__ Wt, const int ldw,
    void* __restrict__ outp, float* __restrict__ alds /* [64][130] */)
{
    constexpr int NJB = NTOT / 16;
    const int jb = gblk % NJB;
    const int ks = gblk / NJB;
    const int lane = t & 63;
    const int wvid = __builtin_amdgcn_readfirstlane(t >> 6);
    const int j0 = jb * 16 + wvid * 2;
    const int k0 = ks * KRANGE;

    double dac[2][2];
    dac[0][0] = 0.0; dac[0][1] = 0.0; dac[1][0] = 0.0; dac[1][1] = 0.0;

    const float* wbase = Wt + (size_t)j0 * ldw;

    for (int kc = 0; kc < KRANGE; kc += 64) {
        const int kg = k0 + kc;
        __syncthreads();
        #pragma unroll
        for (int q = 0; q < 4; ++q) {
            const int f4 = t + 512 * q;
            const int bb = f4 >> 4, c4 = f4 & 15;
            const float4 v = *reinterpret_cast<const float4*>(A + (size_t)bb * lda + kg + c4 * 4);
            alds[(c4*4+0)*130 + bb] = v.x;
            alds[(c4*4+1)*130 + bb] = v.y;
            alds[(c4*4+2)*130 + bb] = v.z;
            alds[(c4*4+3)*130 + bb] = v.w;
        }
        __syncthreads();
        const float* wr = wbase + kg;
        #pragma unroll
        for (int kk16 = 0; kk16 < 64; kk16 += 16) {
            float fa[2][2];
            fa[0][0] = 0.f; fa[0][1] = 0.f; fa[1][0] = 0.f; fa[1][1] = 0.f;
            #pragma unroll
            for (int kk = 0; kk < 16; ++kk) {
                const int k = kk16 + kk;
                const float2 av = *reinterpret_cast<const float2*>(&alds[k*130 + 2*lane]);
                #pragma unroll
                for (int jj = 0; jj < 2; ++jj) {
                    const float wvv = wr[jj*ldw + k];
                    fa[jj][0] = fmaf(wvv, av.x, fa[jj][0]);
                    fa[jj][1] = fmaf(wvv, av.y, fa[jj][1]);
                }
            }
            #pragma unroll
            for (int jj = 0; jj < 2; ++jj) {
                dac[jj][0] += (double)fa[jj][0];
                dac[jj][1] += (double)fa[jj][1];
            }
        }
    }
    #pragma unroll
    for (int i = 0; i < 2; ++i) {
        const int b = 2*lane + i;
        const size_t base = ((size_t)ks * BB + b) * NTOT + j0;
        if constexpr (F64OUT) {
            double* o = (double*)outp;
            o[base + 0] = dac[0][i];
            o[base + 1] = dac[1][i];
        } else {
            float* o = (float*)outp;
            o[base + 0] = (float)dac[0][i];
            o[base + 1] = (float)dac[1][i];
        }
    }
}

// ---------------- 32-col tiled GEMM stage (R0-proven geometry: 8 waves x 4 cols) ----------------
// 8 FMA per ds_read_b64 (2x gemm16); per-output-element math bit-identical to gemm16
// (same K-split, same ascending 16-k f32 chunks, same fmaf order — only j->block map differs).
template<int NTOT, int KRANGE, bool F64OUT>
__device__ __forceinline__ void gemm32(const int gblk, const int t,
    const float* __restrict__ A, const int lda,
    const float* __restrict__ Wt, const int ldw,
    void* __restrict__ outp, float* __restrict__ alds /* [64][130] */)
{
    constexpr int NJB = NTOT / 32;
    const int jb = gblk % NJB;
    const int ks = gblk / NJB;
    const int lane = t & 63;
    const int wvid = __builtin_amdgcn_readfirstlane(t >> 6);
    const int j0 = jb * 32 + wvid * 4;
    const int k0 = ks * KRANGE;

    double dac[4][2];
    #pragma unroll
    for (int jj = 0; jj < 4; ++jj) { dac[jj][0] = 0.0; dac[jj][1] = 0.0; }

    const float* wbase = Wt + (size_t)j0 * ldw;

    for (int kc = 0; kc < KRANGE; kc += 64) {
        const int kg = k0 + kc;
        __syncthreads();
        #pragma unroll
        for (int q = 0; q < 4; ++q) {
            const int f4 = t + 512 * q;
            const int bb = f4 >> 4, c4 = f4 & 15;
            const float4 v = *reinterpret_cast<const float4*>(A + (size_t)bb * lda + kg + c4 * 4);
            alds[(c4*4+0)*130 + bb] = v.x;
            alds[(c4*4+1)*130 + bb] = v.y;
            alds[(c4*4+2)*130 + bb] = v.z;
            alds[(c4*4+3)*130 + bb] = v.w;
        }
        __syncthreads();
        const float* wr = wbase + kg;
        #pragma unroll
        for (int kk16 = 0; kk16 < 64; kk16 += 16) {
            float fa[4][2];
            #pragma unroll
            for (int jj = 0; jj < 4; ++jj) { fa[jj][0] = 0.f; fa[jj][1] = 0.f; }
            #pragma unroll
            for (int kk = 0; kk < 16; ++kk) {
                const int k = kk16 + kk;
                const float2 av = *reinterpret_cast<const float2*>(&alds[k*130 + 2*lane]);
                #pragma unroll
                for (int jj = 0; jj < 4; ++jj) {
                    const float wvv = wr[jj*ldw + k];
                    fa[jj][0] = fmaf(wvv, av.x, fa[jj][0]);
                    fa[jj][1] = fmaf(wvv, av.y, fa[jj][1]);
                }
            }
            #pragma unroll
            for (int jj = 0; jj < 4; ++jj) {
                dac[jj][0] += (double)fa[jj][0];
                dac[jj][1] += (double)fa[jj][1];
            }
        }
    }
    #pragma unroll
    for (int i = 0; i < 2; ++i) {
        const int b = 2*lane + i;
        const size_t base = ((size_t)ks * BB + b) * NTOT + j0;
        if constexpr (F64OUT) {
            double* o = (double*)outp;
            #pragma unroll
            for (int jj = 0; jj < 4; ++jj) o[base + jj] = dac[jj][i];
        } else {
            float* o = (float*)outp;
            #pragma unroll
            for (int jj = 0; jj < 4; ++jj) o[base + jj] = (float)dac[jj][i];
        }
    }
}

// ---------------- L1: combo = gemm1 32-col (128) | gemm2i 32-col (128) | lengths (128) -----------
// 384 blocks x 8 waves = 3 waves/SIMD co-scheduled; xp/op4i values bit-identical to R3.
__global__ __launch_bounds__(512)
void k_combo(const float* __restrict__ input, const float* __restrict__ Wi,
             const float* __restrict__ Wo, const unsigned char* __restrict__ mask,
             double* __restrict__ xp, float* __restrict__ opi, int* __restrict__ lengths)
{
    __shared__ __align__(16) float alds[64*130];
    const int blk = blockIdx.x, t = threadIdx.x;
    if (blk < 128) {
        // x partials = input @ Wi^T  (f64 partials, 4 splits, 32-col blocks)
        gemm32<1024, 256, true>(blk, t, input, DIN, Wi, DIN, xp, alds);
    } else if (blk < 256) {
        // opi[0..3] = input @ Wo[:,1024:]^T
        gemm32<1024, 256, false>(blk - 128, t, input, DIN, Wo + 1024, DIN + DSRC, opi, alds);
    } else {
        const int b = blk - 256;
        const bool is_u8 = (mask[(size_t)SS*BB - 1] != 0);
        int cnt = 0;
        if (is_u8) {
            #pragma unroll
            for (int q = 0; q < 4; ++q)
                cnt += (mask[(size_t)(t + 512*q)*BB + b] != 0) ? 1 : 0;
        } else {
            const int* m32 = (const int*)mask;
            #pragma unroll
            for (int q = 0; q < 4; ++q)
                cnt += (m32[(size_t)(t + 512*q)*BB + b] != 0) ? 1 : 0;
        }
        int* red = (int*)alds;
        red[t] = cnt;
        __syncthreads();
        for (int st = 256; st >= 1; st >>= 1) {
            if (t < st) red[t] += red[t + st];
            __syncthreads();
        }
        if (t == 0) lengths[b] = SS - red[0];
    }
}

// ---------------- L2: reduce xp (4 f64 partials) -> x32 (R3 verbatim) ----------------
__global__ __launch_bounds__(512)
void k_xred(const double* __restrict__ xp, float* __restrict__ x32)
{
    const int i = blockIdx.x * 512 + threadIdx.x;
    double s = 0.0;
    #pragma unroll
    for (int ks = 0; ks < 4; ++ks) s += xp[(size_t)ks * (BB*DSRC) + i];
    x32[i] = (float)s;
}

// ---------------- L3: fc1 partials = x32 @ W1^T (R3 verbatim) ----------------
__global__ __launch_bounds__(512)
void k_fc1(const float* __restrict__ x32, const float* __restrict__ W1, double* __restrict__ z1p)
{
    __shared__ __align__(16) float alds[64*130];
    gemm16<512, 256, true>(blockIdx.x, threadIdx.x, x32, DSRC, W1, DIN, z1p, alds);
}

// ---------------- L4: fc2: z1 reduce + tanh + dot(W2) + sigmoid -> W0, p, gtab, ws/we ------------
__global__ __launch_bounds__(64)
void k_fc2(const double* __restrict__ z1p, const float* __restrict__ b1,
           const float* __restrict__ W2f, const float* __restrict__ b2,
           const int* __restrict__ lengths, int* __restrict__ wsi,
           float* __restrict__ pbuf, float* __restrict__ gtab, float* __restrict__ dout)
{
    const int b = blockIdx.x, lane = threadIdx.x;
    double part = 0.0;
    #pragma unroll
    for (int q = 0; q < 8; ++q) {
        const int h = lane + 64*q;
        double z = 0.0;
        #pragma unroll
        for (int ks = 0; ks < 4; ++ks) z += z1p[((size_t)ks*BB + b)*HH + h];
        z += (double)b1[h];
        part += tanh(z) * (double)W2f[h];
    }
    #pragma unroll
    for (int off = 32; off >= 1; off >>= 1) part += __shfl_xor(part, off);
    const double z2  = part + (double)b2[0];
    const double sig = 1.0 / (1.0 + exp(-z2));
    const double wsf = (double)lengths[b] * sig;   // p - W
    int W0 = (int)rint(wsf);
    if (W0 < 0) W0 = 0;
    if (W0 > SS - WLEN) W0 = SS - WLEN;
    const float pf = (float)(wsf + 64.0);
    if (lane == 0) {
        wsi[b]  = W0;
        pbuf[b] = pf;
        dout[DO_WS + b] = (float)W0;
        dout[DO_WE + b] = (float)(W0 + WLEN);
    }
    #pragma unroll
    for (int q = 0; q < 3; ++q) {
        const int w = lane + 64*q;
        if (w < GW) {
            float g = 0.f;
            if (w < WLEN) {
                const float d = (float)(W0 + w) - pf;
                g = expf(d*d * (-1.0f/2048.0f));
            }
            gtab[b*GW + w] = g;
        }
    }
}

// ---------------- L5: per-(b, w-chunk) scores + local softmax + partial c (R3 verbatim) ----------
__global__ __launch_bounds__(256)
void k_score(const float* __restrict__ x32, const float* __restrict__ src,
             const int* __restrict__ wsi, const float* __restrict__ pbuf,
             const int* __restrict__ lengths, const float* __restrict__ gtab,
             float* __restrict__ cpart, float* __restrict__ mpart,
             float* __restrict__ lpart, float* __restrict__ spart)
{
    const int wc = blockIdx.x, b = blockIdx.y;
    const int t = threadIdx.x, lane = t & 63, wv = t >> 6;
    const int   w0 = wsi[b];
    const int   L  = lengths[b];

    const float4 x4 = *reinterpret_cast<const float4*>(x32 + b*DSRC + 4*t);

    float4 sel[WCH];
    #pragma unroll
    for (int i = 0; i < WCH; ++i) {
        const int w = wc*WCH + i;
        if (w < WLEN) {
            const size_t off = ((size_t)(w0 + w) * BB + b) * DSRC + 4*t;
            sel[i] = *reinterpret_cast<const float4*>(src + off);
        } else sel[i] = make_float4(0.f, 0.f, 0.f, 0.f);
    }

    float w_[32];
    #pragma unroll
    for (int i = 0; i < WCH; ++i)
        w_[i] = fmaf(x4.x, sel[i].x, fmaf(x4.y, sel[i].y, fmaf(x4.z, sel[i].z, x4.w * sel[i].w)));
    #pragma unroll
    for (int i = WCH; i < 32; ++i) w_[i] = 0.f;

    #pragma unroll
    for (int k = 0; k < 5; ++k) {
        const int dist = 1 << k;
        const bool hi = (lane >> k) & 1;
        const int n2 = 32 >> (k + 1);
        #pragma unroll
        for (int i = 0; i < n2; ++i) {
            const float keep = hi ? w_[2*i+1] : w_[2*i];
            const float send = hi ? w_[2*i]   : w_[2*i+1];
            w_[i] = keep + __shfl_xor(send, dist);
        }
    }
    const float tot = w_[0] + __shfl_xor(w_[0], 32);   // full 64-lane sum of row (lane&31)

    __shared__ float red[WCH][4];
    __shared__ float s_sh[WCH];
    if (lane < WCH) red[lane][wv] = tot;
    __syncthreads();
    if (t < WCH) {
        const int w = wc*WCH + t;
        float s;
        if (w < WLEN) {
            const float sum = red[t][0] + red[t][1] + red[t][2] + red[t][3];
            const int pos = w0 + w;
            s = (pos >= WW && pos < L + WW) ? sum : 1e-14f;
        } else s = -INFINITY;
        s_sh[t] = s;
    }
    __syncthreads();

    float sv[WCH];
    #pragma unroll
    for (int i = 0; i < WCH; ++i) sv[i] = s_sh[i];
    float m_loc = -INFINITY;
    #pragma unroll
    for (int i = 0; i < WCH; ++i) m_loc = fmaxf(m_loc, sv[i]);
    float l_loc = 0.f;
    float4 c = make_float4(0.f, 0.f, 0.f, 0.f);
    #pragma unroll
    for (int i = 0; i < WCH; ++i) {
        const float e = expf(sv[i] - m_loc);       // -inf -> 0 for w >= WLEN
        l_loc += e;
        const float g = gtab[b*GW + wc*WCH + i];   // 0 beyond WLEN
        const float wt = e * g;
        c.x = fmaf(wt, sel[i].x, c.x);
        c.y = fmaf(wt, sel[i].y, c.y);
        c.z = fmaf(wt, sel[i].z, c.z);
        c.w = fmaf(wt, sel[i].w, c.w);
    }
    *reinterpret_cast<float4*>(cpart + ((size_t)(b*8 + wc))*DSRC + 4*t) = c;
    if (t == 0) { mpart[b*8 + wc] = m_loc; lpart[b*8 + wc] = l_loc; }
    if (t < WCH) spart[(b*8 + wc)*WCH + t] = s_sh[t];
}

// ---------------- L6: merge 8 partials per b -> c32 + a output (R3 verbatim) ----------------
__global__ __launch_bounds__(256)
void k_merge(const float* __restrict__ cpart, const float* __restrict__ mpart,
             const float* __restrict__ lpart, const float* __restrict__ spart,
             const float* __restrict__ gtab, float* __restrict__ c32,
             float* __restrict__ dout)
{
    const int b = blockIdx.x, t = threadIdx.x;
    __shared__ float mv[8], lv[8];
    if (t < 8) { mv[t] = mpart[b*8 + t]; lv[t] = lpart[b*8 + t]; }
    __syncthreads();
    float m = -INFINITY;
    #pragma unroll
    for (int i = 0; i < 8; ++i) m = fmaxf(m, mv[i]);
    float l = 0.f;
    float fac[8];
    #pragma unroll
    for (int i = 0; i < 8; ++i) { fac[i] = expf(mv[i] - m); l = fmaf(lv[i], fac[i], l); }
    const float inv = 1.0f / l;

    float4 c = make_float4(0.f, 0.f, 0.f, 0.f);
    #pragma unroll
    for (int i = 0; i < 8; ++i) {
        const float4 cp = *reinterpret_cast<const float4*>(cpart + ((size_t)(b*8 + i))*DSRC + 4*t);
        c.x = fmaf(cp.x, fac[i], c.x);
        c.y = fmaf(cp.y, fac[i], c.y);
        c.z = fmaf(cp.z, fac[i], c.z);
        c.w = fmaf(cp.w, fac[i], c.w);
    }
    c.x *= inv; c.y *= inv; c.z *= inv; c.w *= inv;
    *reinterpret_cast<float4*>(c32 + (size_t)b*DSRC + 4*t) = c;

    if (t < WLEN) {
        const int wc = t / WCH, i = t % WCH;
        const float s = spart[(b*8 + wc)*WCH + i];
        const float g = gtab[b*GW + t];
        dout[DO_A + b*WLEN + t] = expf(s - m) * inv * g;
    }
}

// ---------------- L7: opc[0..7] = c32 @ Wo[:, :1024]^T (32-col, 8 splits, 256 blocks) ------------
__global__ __launch_bounds__(512)
void k_gemm2c(const float* __restrict__ c32, const float* __restrict__ Wo, float* __restrict__ opc)
{
    __shared__ __align__(16) float alds[64*130];
    gemm32<1024, 128, false>(blockIdx.x, threadIdx.x, c32, DSRC, Wo, DIN + DSRC, opc, alds);
}

// ---------------- L8: reduce 8 c-partials + 4 input-partials + tanh -> out ----------------
__global__ __launch_bounds__(512)
void k_outred(const float* __restrict__ opc, const float* __restrict__ opi,
              float* __restrict__ dout)
{
    const int i = blockIdx.x * 512 + threadIdx.x;
    float s = 0.f;
    #pragma unroll
    for (int ks = 0; ks < 8; ++ks) s += opc[(size_t)ks * (BB*DOUT) + i];
    #pragma unroll
    for (int ks = 0; ks < 4; ++ks) s += opi[(size_t)ks * (BB*DOUT) + i];
    dout[i] = tanhf(s);
}

extern "C" void kernel_launch(void* const* d_in, const int* in_sizes, int n_in,
                              void* d_out, int out_size, void* d_ws, size_t ws_size,
                              hipStream_t stream)
{
    const float* input = (const float*)d_in[0];
    const float* src   = (const float*)d_in[1];
    const unsigned char* mask = (const unsigned char*)d_in[2];
    const float* Wi = (const float*)d_in[3];
    const float* Wo = (const float*)d_in[4];
    const float* W1 = (const float*)d_in[5];
    const float* b1 = (const float*)d_in[6];
    const float* W2 = (const float*)d_in[7];
    const float* b2 = (const float*)d_in[8];
    float* out = (float*)d_out;

    if (ws_size < (size_t)WS_NEED) return;

    char* ws = (char*)d_ws;
    int*    wsi     = (int*)   (ws + OFF_WSI);
    float*  pbuf    = (float*) (ws + OFF_P);
    int*    lengths = (int*)   (ws + OFF_LEN);
    float*  gtab    = (float*) (ws + OFF_GTAB);
    double* xp      = (double*)(ws + OFF_XP);
    float*  x32     = (float*) (ws + OFF_X32);
    double* z1p     = (double*)(ws + OFF_Z1P);
    float*  c32     = (float*) (ws + OFF_C32);
    float*  cpart   = (float*) (ws + OFF_CPART);
    float*  mpart   = (float*) (ws + OFF_MPART);
    float*  lpart   = (float*) (ws + OFF_LPART);
    float*  spart   = (float*) (ws + OFF_SPART);
    float*  opc     = (float*) (ws + OFF_OPC);
    float*  opi     = (float*) (ws + OFF_OPI);

    // L1: gemm1 (32-col) || gemm2-input-half (32-col) || lengths
    k_combo<<<384, 512, 0, stream>>>(input, Wi, Wo, mask, xp, opi, lengths);
    // L2: x32 = f64-reduce(xp)
    k_xred<<<256, 512, 0, stream>>>(xp, x32);
    // L3: z1 partials = x32 @ W1^T
    k_fc1<<<128, 512, 0, stream>>>(x32, W1, z1p);
    // L4: fc2 -> W0/p/gtab/ws/we
    k_fc2<<<128, 64, 0, stream>>>(z1p, b1, W2, b2, lengths, wsi, pbuf, gtab, out);
    // L5: scores + local softmax + partial c
    k_score<<<dim3(8,128), 256, 0, stream>>>(x32, src, wsi, pbuf, lengths, gtab,
                                             cpart, mpart, lpart, spart);
    // L6: merge partials -> c32 + a
    k_merge<<<128, 256, 0, stream>>>(cpart, mpart, lpart, spart, gtab, c32, out);
    // L7: opc[0..7] = c32 @ Wo_c^T (32-col, 256 blocks)
    k_gemm2c<<<256, 512, 0, stream>>>(c32, Wo, opc);
    // L8: out = tanh(sum opc + sum opi)
    k_outred<<<256, 512, 0, stream>>>(opc, opi, out);
}

// Round 11
// 75.445 us; speedup vs baseline: 1.2700x; 1.1327x over previous
//
#include <hip/hip_runtime.h>
#include <math.h>

#define BB   128
#define SS   2048
#define DIN  1024
#define DSRC 1024
#define DOUT 1024
#define WW   64
#define WLEN 129
#define HH   512
#define WCH  17     // w-chunk per score block; 8 chunks cover 136 >= 129
#define GW   136    // gaussian table width (WLEN padded)

// workspace layout (bytes)
#define OFF_WSI   0
#define OFF_P     512
#define OFF_LEN   1024
#define OFF_GTAB  4096        // float[128][136]
#define OFF_XP    73728       // double[4][128][1024] = 4 MB
#define OFF_X32   4268032     // float[128][1024]
#define OFF_Z1P   4792320     // double[4][128][512] = 2 MB
#define OFF_C32   6889472     // float[128][1024]
#define OFF_CPART 7413760     // float[128][8][1024] = 4 MB
#define OFF_MPART 11608064
#define OFF_LPART 11612160
#define OFF_SPART 11616256    // float[128][8][17]
#define OFF_OP    11685888    // float[8][128][1024] = 4 MB
#define WS_NEED   15880192

// d_out layout (floats)
#define DO_A    (BB*DOUT)        // 131072
#define DO_WS   (DO_A + BB*WLEN) // 147584
#define DO_WE   (DO_WS + BB)     // 147712

// ---------------- 16-col tiled GEMM stage (f32 products, f64 chunk accumulation) ----------------
// R3-proven geometry: NJB = NTOT/16 j-blocks, 4 splits, 8 waves x 2 cols, lanes hold 2 b rows.
template<int NTOT, int KRANGE, bool F64OUT>
__device__ __forceinline__ void gemm16(const int gblk, const int t,
    const float* __restrict__ A, const int lda,
    const float* __restrict__ Wt, const int ldw,
    void* __restrict__ outp, float* __restrict__ alds /* [64][130] */)
{
    constexpr int NJB = NTOT / 16;
    const int jb = gblk % NJB;
    const int ks = gblk / NJB;
    const int lane = t & 63;
    const int wvid = __builtin_amdgcn_readfirstlane(t >> 6);
    const int j0 = jb * 16 + wvid * 2;
    const int k0 = ks * KRANGE;

    double dac[2][2];
    dac[0][0] = 0.0; dac[0][1] = 0.0; dac[1][0] = 0.0; dac[1][1] = 0.0;

    const float* wbase = Wt + (size_t)j0 * ldw;

    for (int kc = 0; kc < KRANGE; kc += 64) {
        const int kg = k0 + kc;
        __syncthreads();
        #pragma unroll
        for (int q = 0; q < 4; ++q) {
            const int f4 = t + 512 * q;
            const int bb = f4 >> 4, c4 = f4 & 15;
            const float4 v = *reinterpret_cast<const float4*>(A + (size_t)bb * lda + kg + c4 * 4);
            alds[(c4*4+0)*130 + bb] = v.x;
            alds[(c4*4+1)*130 + bb] = v.y;
            alds[(c4*4+2)*130 + bb] = v.z;
            alds[(c4*4+3)*130 + bb] = v.w;
        }
        __syncthreads();
        const float* wr = wbase + kg;
        #pragma unroll
        for (int kk16 = 0; kk16 < 64; kk16 += 16) {
            float fa[2][2];
            fa[0][0] = 0.f; fa[0][1] = 0.f; fa[1][0] = 0.f; fa[1][1] = 0.f;
            #pragma unroll
            for (int kk = 0; kk < 16; ++kk) {
                const int k = kk16 + kk;
                const float2 av = *reinterpret_cast<const float2*>(&alds[k*130 + 2*lane]);
                #pragma unroll
                for (int jj = 0; jj < 2; ++jj) {
                    const float wvv = wr[jj*ldw + k];
                    fa[jj][0] = fmaf(wvv, av.x, fa[jj][0]);
                    fa[jj][1] = fmaf(wvv, av.y, fa[jj][1]);
                }
            }
            #pragma unroll
            for (int jj = 0; jj < 2; ++jj) {
                dac[jj][0] += (double)fa[jj][0];
                dac[jj][1] += (double)fa[jj][1];
            }
        }
    }
    #pragma unroll
    for (int i = 0; i < 2; ++i) {
        const int b = 2*lane + i;
        const size_t base = ((size_t)ks * BB + b) * NTOT + j0;
        if constexpr (F64OUT) {
            double* o = (double*)outp;
            o[base + 0] = dac[0][i];
            o[base + 1] = dac[1][i];
        } else {
            float* o = (float*)outp;
            o[base + 0] = (float)dac[0][i];
            o[base + 1] = (float)dac[1][i];
        }
    }
}

// ---------------- L1: combo = gemm1 (256) | gemm2-input-half (256) | lengths (128) ----------------
__global__ __launch_bounds__(512)
void k_combo(const float* __restrict__ input, const float* __restrict__ Wi,
             const float* __restrict__ Wo, const unsigned char* __restrict__ mask,
             double* __restrict__ xp, float* __restrict__ op4, int* __restrict__ lengths)
{
    __shared__ __align__(16) float alds[64*130];
    const int blk = blockIdx.x, t = threadIdx.x;
    if (blk < 256) {
        // x partials = input @ Wi^T  (f64 partials, 4 splits)
        gemm16<1024, 256, true>(blk, t, input, DIN, Wi, DIN, xp, alds);
    } else if (blk < 512) {
        // op[4..7] = input @ Wo[:,1024:]^T  (independent of everything downstream)
        gemm16<1024, 256, false>(blk - 256, t, input, DIN, Wo + 1024, DIN + DSRC, op4, alds);
    } else {
        const int b = blk - 512;
        const bool is_u8 = (mask[(size_t)SS*BB - 1] != 0);
        int cnt = 0;
        if (is_u8) {
            #pragma unroll
            for (int q = 0; q < 4; ++q)
                cnt += (mask[(size_t)(t + 512*q)*BB + b] != 0) ? 1 : 0;
        } else {
            const int* m32 = (const int*)mask;
            #pragma unroll
            for (int q = 0; q < 4; ++q)
                cnt += (m32[(size_t)(t + 512*q)*BB + b] != 0) ? 1 : 0;
        }
        int* red = (int*)alds;
        red[t] = cnt;
        __syncthreads();
        for (int st = 256; st >= 1; st >>= 1) {
            if (t < st) red[t] += red[t + st];
            __syncthreads();
        }
        if (t == 0) lengths[b] = SS - red[0];
    }
}

// ---------------- L2: reduce xp (4 f64 partials) -> x32 ----------------
__global__ __launch_bounds__(512)
void k_xred(const double* __restrict__ xp, float* __restrict__ x32)
{
    const int i = blockIdx.x * 512 + threadIdx.x;
    double s = 0.0;
    #pragma unroll
    for (int ks = 0; ks < 4; ++ks) s += xp[(size_t)ks * (BB*DSRC) + i];
    x32[i] = (float)s;
}

// ---------------- L3: fc1 partials = x32 @ W1^T ----------------
__global__ __launch_bounds__(512)
void k_fc1(const float* __restrict__ x32, const float* __restrict__ W1, double* __restrict__ z1p)
{
    __shared__ __align__(16) float alds[64*130];
    gemm16<512, 256, true>(blockIdx.x, threadIdx.x, x32, DSRC, W1, DIN, z1p, alds);
}

// ---------------- L4: fc2: z1 reduce + tanh + dot(W2) + sigmoid -> W0, p, gtab, ws/we ------------
__global__ __launch_bounds__(64)
void k_fc2(const double* __restrict__ z1p, const float* __restrict__ b1,
           const float* __restrict__ W2f, const float* __restrict__ b2,
           const int* __restrict__ lengths, int* __restrict__ wsi,
           float* __restrict__ pbuf, float* __restrict__ gtab, float* __restrict__ dout)
{
    const int b = blockIdx.x, lane = threadIdx.x;
    double part = 0.0;
    #pragma unroll
    for (int q = 0; q < 8; ++q) {
        const int h = lane + 64*q;
        double z = 0.0;
        #pragma unroll
        for (int ks = 0; ks < 4; ++ks) z += z1p[((size_t)ks*BB + b)*HH + h];
        z += (double)b1[h];
        part += tanh(z) * (double)W2f[h];
    }
    #pragma unroll
    for (int off = 32; off >= 1; off >>= 1) part += __shfl_xor(part, off);
    // all lanes now hold the full sum -> replicate the (deterministic) f64 tail
    const double z2  = part + (double)b2[0];
    const double sig = 1.0 / (1.0 + exp(-z2));
    const double wsf = (double)lengths[b] * sig;   // p - W
    int W0 = (int)rint(wsf);
    if (W0 < 0) W0 = 0;
    if (W0 > SS - WLEN) W0 = SS - WLEN;
    const float pf = (float)(wsf + 64.0);
    if (lane == 0) {
        wsi[b]  = W0;
        pbuf[b] = pf;
        dout[DO_WS + b] = (float)W0;
        dout[DO_WE + b] = (float)(W0 + WLEN);
    }
    #pragma unroll
    for (int q = 0; q < 3; ++q) {
        const int w = lane + 64*q;
        if (w < GW) {
            float g = 0.f;
            if (w < WLEN) {
                const float d = (float)(W0 + w) - pf;
                g = expf(d*d * (-1.0f/2048.0f));
            }
            gtab[b*GW + w] = g;
        }
    }
}

// ---------------- L5: per-(b, w-chunk) scores + local softmax + partial c ----------------
// grid (8, 128), 256 threads. Multi-value butterfly: 32 shuffle-adds instead of 102.
__global__ __launch_bounds__(256)
void k_score(const float* __restrict__ x32, const float* __restrict__ src,
             const int* __restrict__ wsi, const float* __restrict__ pbuf,
             const int* __restrict__ lengths, const float* __restrict__ gtab,
             float* __restrict__ cpart, float* __restrict__ mpart,
             float* __restrict__ lpart, float* __restrict__ spart)
{
    const int wc = blockIdx.x, b = blockIdx.y;
    const int t = threadIdx.x, lane = t & 63, wv = t >> 6;
    const int   w0 = wsi[b];
    const int   L  = lengths[b];

    const float4 x4 = *reinterpret_cast<const float4*>(x32 + b*DSRC + 4*t);

    float4 sel[WCH];
    #pragma unroll
    for (int i = 0; i < WCH; ++i) {
        const int w = wc*WCH + i;
        if (w < WLEN) {
            const size_t off = ((size_t)(w0 + w) * BB + b) * DSRC + 4*t;
            sel[i] = *reinterpret_cast<const float4*>(src + off);
        } else sel[i] = make_float4(0.f, 0.f, 0.f, 0.f);
    }

    // per-lane partial dot for each of 17 rows
    float w_[32];
    #pragma unroll
    for (int i = 0; i < WCH; ++i)
        w_[i] = fmaf(x4.x, sel[i].x, fmaf(x4.y, sel[i].y, fmaf(x4.z, sel[i].z, x4.w * sel[i].w)));
    #pragma unroll
    for (int i = WCH; i < 32; ++i) w_[i] = 0.f;

    // multi-value butterfly: after 5 levels lane holds value (lane&31) summed over its 32-lane half
    #pragma unroll
    for (int k = 0; k < 5; ++k) {
        const int dist = 1 << k;
        const bool hi = (lane >> k) & 1;
        const int n2 = 32 >> (k + 1);
        #pragma unroll
        for (int i = 0; i < n2; ++i) {
            const float keep = hi ? w_[2*i+1] : w_[2*i];
            const float send = hi ? w_[2*i]   : w_[2*i+1];
            w_[i] = keep + __shfl_xor(send, dist);
        }
    }
    const float tot = w_[0] + __shfl_xor(w_[0], 32);   // full 64-lane sum of row (lane&31)

    __shared__ float red[WCH][4];
    __shared__ float s_sh[WCH];
    if (lane < WCH) red[lane][wv] = tot;
    __syncthreads();
    if (t < WCH) {
        const int w = wc*WCH + t;
        float s;
        if (w < WLEN) {
            const float sum = red[t][0] + red[t][1] + red[t][2] + red[t][3];
            const int pos = w0 + w;
            s = (pos >= WW && pos < L + WW) ? sum : 1e-14f;
        } else s = -INFINITY;
        s_sh[t] = s;
    }
    __syncthreads();

    float sv[WCH];
    #pragma unroll
    for (int i = 0; i < WCH; ++i) sv[i] = s_sh[i];
    float m_loc = -INFINITY;
    #pragma unroll
    for (int i = 0; i < WCH; ++i) m_loc = fmaxf(m_loc, sv[i]);
    float l_loc = 0.f;
    float4 c = make_float4(0.f, 0.f, 0.f, 0.f);
    #pragma unroll
    for (int i = 0; i < WCH; ++i) {
        const float e = expf(sv[i] - m_loc);       // -inf -> 0 for w >= WLEN
        l_loc += e;
        const float g = gtab[b*GW + wc*WCH + i];   // 0 beyond WLEN
        const float wt = e * g;
        c.x = fmaf(wt, sel[i].x, c.x);
        c.y = fmaf(wt, sel[i].y, c.y);
        c.z = fmaf(wt, sel[i].z, c.z);
        c.w = fmaf(wt, sel[i].w, c.w);
    }
    *reinterpret_cast<float4*>(cpart + ((size_t)(b*8 + wc))*DSRC + 4*t) = c;
    if (t == 0) { mpart[b*8 + wc] = m_loc; lpart[b*8 + wc] = l_loc; }
    if (t < WCH) spart[(b*8 + wc)*WCH + t] = s_sh[t];
}

// ---------------- L6: merge 8 partials per b -> c32 + a output ----------------
__global__ __launch_bounds__(256)
void k_merge(const float* __restrict__ cpart, const float* __restrict__ mpart,
             const float* __restrict__ lpart, const float* __restrict__ spart,
             const float* __restrict__ gtab, float* __restrict__ c32,
             float* __restrict__ dout)
{
    const int b = blockIdx.x, t = threadIdx.x;
    __shared__ float mv[8], lv[8];
    if (t < 8) { mv[t] = mpart[b*8 + t]; lv[t] = lpart[b*8 + t]; }
    __syncthreads();
    float m = -INFINITY;
    #pragma unroll
    for (int i = 0; i < 8; ++i) m = fmaxf(m, mv[i]);
    float l = 0.f;
    float fac[8];
    #pragma unroll
    for (int i = 0; i < 8; ++i) { fac[i] = expf(mv[i] - m); l = fmaf(lv[i], fac[i], l); }
    const float inv = 1.0f / l;

    float4 c = make_float4(0.f, 0.f, 0.f, 0.f);
    #pragma unroll
    for (int i = 0; i < 8; ++i) {
        const float4 cp = *reinterpret_cast<const float4*>(cpart + ((size_t)(b*8 + i))*DSRC + 4*t);
        c.x = fmaf(cp.x, fac[i], c.x);
        c.y = fmaf(cp.y, fac[i], c.y);
        c.z = fmaf(cp.z, fac[i], c.z);
        c.w = fmaf(cp.w, fac[i], c.w);
    }
    c.x *= inv; c.y *= inv; c.z *= inv; c.w *= inv;
    *reinterpret_cast<float4*>(c32 + (size_t)b*DSRC + 4*t) = c;

    if (t < WLEN) {
        const int wc = t / WCH, i = t % WCH;
        const float s = spart[(b*8 + wc)*WCH + i];
        const float g = gtab[b*GW + t];
        dout[DO_A + b*WLEN + t] = expf(s - m) * inv * g;
    }
}

// ---------------- L7: op[0..3] = c32 @ Wo[:, :1024]^T ----------------
__global__ __launch_bounds__(512)
void k_gemm2c(const float* __restrict__ c32, const float* __restrict__ Wo, float* __restrict__ op)
{
    __shared__ __align__(16) float alds[64*130];
    gemm16<1024, 256, false>(blockIdx.x, threadIdx.x, c32, DSRC, Wo, DIN + DSRC, op, alds);
}

// ---------------- L8: reduce 8 op partials + tanh -> out ----------------
__global__ __launch_bounds__(512)
void k_outred(const float* __restrict__ op, float* __restrict__ dout)
{
    const int i = blockIdx.x * 512 + threadIdx.x;
    float s = 0.f;
    #pragma unroll
    for (int ks = 0; ks < 8; ++ks) s += op[(size_t)ks * (BB*DOUT) + i];
    dout[i] = tanhf(s);
}

extern "C" void kernel_launch(void* const* d_in, const int* in_sizes, int n_in,
                              void* d_out, int out_size, void* d_ws, size_t ws_size,
                              hipStream_t stream)
{
    const float* input = (const float*)d_in[0];
    const float* src   = (const float*)d_in[1];
    const unsigned char* mask = (const unsigned char*)d_in[2];
    const float* Wi = (const float*)d_in[3];
    const float* Wo = (const float*)d_in[4];
    const float* W1 = (const float*)d_in[5];
    const float* b1 = (const float*)d_in[6];
    const float* W2 = (const float*)d_in[7];
    const float* b2 = (const float*)d_in[8];
    float* out = (float*)d_out;

    if (ws_size < (size_t)WS_NEED) return;

    char* ws = (char*)d_ws;
    int*    wsi     = (int*)   (ws + OFF_WSI);
    float*  pbuf    = (float*) (ws + OFF_P);
    int*    lengths = (int*)   (ws + OFF_LEN);
    float*  gtab    = (float*) (ws + OFF_GTAB);
    double* xp      = (double*)(ws + OFF_XP);
    float*  x32     = (float*) (ws + OFF_X32);
    double* z1p     = (double*)(ws + OFF_Z1P);
    float*  c32     = (float*) (ws + OFF_C32);
    float*  cpart   = (float*) (ws + OFF_CPART);
    float*  mpart   = (float*) (ws + OFF_MPART);
    float*  lpart   = (float*) (ws + OFF_LPART);
    float*  spart   = (float*) (ws + OFF_SPART);
    float*  op      = (float*) (ws + OFF_OP);

    // L1: gemm1 || gemm2-input-half || lengths  (all mutually independent)
    k_combo<<<640, 512, 0, stream>>>(input, Wi, Wo, mask, xp, op + 4*(size_t)BB*DOUT, lengths);
    // L2: x32 = f64-reduce(xp)
    k_xred<<<256, 512, 0, stream>>>(xp, x32);
    // L3: z1 partials = x32 @ W1^T
    k_fc1<<<128, 512, 0, stream>>>(x32, W1, z1p);
    // L4: fc2 -> W0/p/gtab/ws/we
    k_fc2<<<128, 64, 0, stream>>>(z1p, b1, W2, b2, lengths, wsi, pbuf, gtab, out);
    // L5: scores + local softmax + partial c
    k_score<<<dim3(8,128), 256, 0, stream>>>(x32, src, wsi, pbuf, lengths, gtab,
                                             cpart, mpart, lpart, spart);
    // L6: merge partials -> c32 + a
    k_merge<<<128, 256, 0, stream>>>(cpart, mpart, lpart, spart, gtab, c32, out);
    // L7: op[0..3] = c32 @ Wo_c^T
    k_gemm2c<<<256, 512, 0, stream>>>(c32, Wo, op);
    // L8: out = tanh(sum op)
    k_outred<<<256, 512, 0, stream>>>(op, out);
}